// Round 6
// baseline (298.716 us; speedup 1.0000x reference)
//
#include <hip/hip_runtime.h>

// Problem constants
#define B_  4
#define S_  2048
#define E_  1024
#define H_  16
#define DK_ 64
#define M_  (B_*S_)   // 8192

typedef __attribute__((ext_vector_type(8)))  short short8;   // 8 bf16 (4 VGPRs)
typedef __attribute__((ext_vector_type(4)))  float f32x4;
typedef __attribute__((ext_vector_type(16))) float f32x16;   // 32x32 MFMA accumulator

#define QSCALE 0.18033688f   // 0.125 * log2(e): folded into Q so p = exp2(score)

// fp32 -> bf16 round-to-nearest-even
__device__ __forceinline__ unsigned short f2b(float f) {
    union { float f; unsigned u; } v; v.f = f;
    unsigned u = v.u;
    return (unsigned short)((u + 0x7fffu + ((u >> 16) & 1u)) >> 16);
}

// async global->LDS, 16 bytes/lane. LDS dest = wave-uniform base + lane*16.
__device__ __forceinline__ void gload_lds16(const unsigned short* g, unsigned short* l) {
    __builtin_amdgcn_global_load_lds((const __attribute__((address_space(1))) void*)g,
                                     (__attribute__((address_space(3))) void*)l, 16, 0, 0);
}

// One launch for all fp32->bf16 converts: x (M*E) then Wq,Wk,Wv,Wo (E*E each).
#define XN4 (M_*E_/4)
#define WN4 (E_*E_/4)
__global__ __launch_bounds__(256) void cvt_all(
    const float* __restrict__ x,
    const float* __restrict__ w0, const float* __restrict__ w1,
    const float* __restrict__ w2, const float* __restrict__ w3,
    unsigned short* __restrict__ xb, unsigned short* __restrict__ wb,
    unsigned short* __restrict__ wob) {
    int i = blockIdx.x * 256 + threadIdx.x;
    const float* src;
    unsigned short* dst;
    int idx;
    if (i < XN4) { src = x; dst = xb; idx = i; }
    else {
        int j = i - XN4;
        int z = j >> 18;              // / WN4
        idx = j & (WN4 - 1);
        src = (z == 0) ? w0 : (z == 1) ? w1 : (z == 2) ? w2 : w3;
        dst = (z < 3) ? wb + (size_t)z * E_ * E_ : wob;
    }
    float4 f = ((const float4*)src)[idx];
    ushort4 o;
    o.x = f2b(f.x); o.y = f2b(f.y); o.z = f2b(f.z); o.w = f2b(f.w);
    ((ushort4*)dst)[idx] = o;
}

// ---------------------------------------------------------------------------
// 128x128-tile GEMM (m97 structure). All epilogues transpose through LDS for
// coalesced b128 global stores. q output pre-scaled by QSCALE.
// ---------------------------------------------------------------------------
__global__ __launch_bounds__(256) void gemm_qkv(
    const unsigned short* __restrict__ xb,   // [M][E]
    const unsigned short* __restrict__ Wb,   // [3][E][E]
    const float* __restrict__ theta,         // [64]
    unsigned short* __restrict__ qb,         // [B*H][S][DK]  (q pre-scaled)
    unsigned short* __restrict__ kb,         // [B*H][S][DK]
    unsigned short* __restrict__ vtb)        // [B*H][DK][S]
{
    __shared__ unsigned short smem[128*144];            // 36864 B
    unsigned short* As = smem;                          // [128][64]
    unsigned short* Bs = smem + 128*64;
    const int tid = threadIdx.x;
    const int w = tid >> 6, lane = tid & 63, quad = lane >> 4, col = lane & 15;
    const int wm = (w & 1) * 64, wn = (w >> 1) * 64;
    const int m0 = blockIdx.x * 128, n0 = blockIdx.y * 128, z = blockIdx.z;
    const unsigned short* Wz = Wb + (size_t)z * E_ * E_;
    const int srow = lane >> 3, schunk = (lane & 7) * 8;

    f32x4 acc[4][4] = {};
    for (int k0 = 0; k0 < E_; k0 += 64) {
        #pragma unroll
        for (int c = 0; c < 4; c++) {
            int row = w*32 + c*8 + srow;
            gload_lds16(&xb[(size_t)(m0+row)*E_ + k0 + schunk], &As[(w*32 + c*8)*64]);
            gload_lds16(&Wz[(size_t)(n0+row)*E_ + k0 + schunk], &Bs[(w*32 + c*8)*64]);
        }
        __syncthreads();
        #pragma unroll
        for (int kk = 0; kk < 64; kk += 32) {
            short8 a[4], b[4];
            #pragma unroll
            for (int i = 0; i < 4; i++)
                a[i] = *(const short8*)&As[(wm + i*16 + col)*64 + kk + quad*8];
            #pragma unroll
            for (int j = 0; j < 4; j++)
                b[j] = *(const short8*)&Bs[(wn + j*16 + col)*64 + kk + quad*8];
            #pragma unroll
            for (int i = 0; i < 4; i++)
                #pragma unroll
                for (int j = 0; j < 4; j++)
                    acc[i][j] = __builtin_amdgcn_mfma_f32_16x16x32_bf16(a[i], b[j], acc[i][j], 0, 0, 0);
        }
        __syncthreads();
    }

    const int bblk = m0 >> 11;            // batch index (tile never crosses S)
    const int sbase = m0 & (S_-1);

    if (z != 2) {
        const float qs = (z == 0) ? QSCALE : 1.0f;
        // C -> smem[m][n] (stride 144), quad-XOR swizzle on n (16-elt granularity)
        #pragma unroll
        for (int j = 0; j < 4; j++) {
            int nl = wn + j*16 + col;
            float th = theta[(n0 + nl) & 63];
            #pragma unroll
            for (int i = 0; i < 4; i++)
                #pragma unroll
                for (int r = 0; r < 4; r++) {
                    int ml = wm + i*16 + quad*4 + r;
                    int nls = nl ^ (((ml >> 2) & 3) << 4);
                    smem[ml*144 + nls] = f2b(__cosf(acc[i][j][r] + th) * qs);
                }
        }
        __syncthreads();
        unsigned short* dst = (z == 0) ? qb : kb;
        const int h0 = n0 >> 6;
        #pragma unroll
        for (int k = 0; k < 8; k++) {
            int idx = k*256 + tid;
            int chunk = idx & 7, seg = idx >> 3;
            int ml = seg >> 1, hh = seg & 1;
            int ch = chunk ^ (((ml >> 2) & 3) << 1);     // de-swizzle (8-elt chunks)
            int4 val = *(const int4*)&smem[ml*144 + hh*64 + ch*8];
            size_t g = ((size_t)(bblk*H_ + h0 + hh)*S_ + sbase + ml)*DK_ + chunk*8;
            *(int4*)&dst[g] = val;
        }
    } else {
        // V: transpose tile (n-major) -> vtb[bh][d][s] coalesced rows
        #pragma unroll
        for (int j = 0; j < 4; j++) {
            int nl = wn + j*16 + col;
            float th = theta[(n0 + nl) & 63];
            #pragma unroll
            for (int i = 0; i < 4; i++)
                #pragma unroll
                for (int r = 0; r < 4; r++)
                    smem[nl*136 + wm + i*16 + quad*4 + r] = f2b(__cosf(acc[i][j][r] + th));
        }
        __syncthreads();
        int row = tid >> 1, halfm = (tid & 1) * 64;     // 2 threads per n-row
        int n = n0 + row, h = n >> 6, d = n & 63;
        size_t base = ((size_t)(bblk*H_ + h)*DK_ + d)*S_ + sbase + halfm;
        #pragma unroll
        for (int k = 0; k < 8; k++)
            *(int4*)&vtb[base + k*8] = *(const int4*)&smem[row*136 + halfm + k*8];
    }
}

// out = ctx @ Wo.T, fp32 output
__global__ __launch_bounds__(256) void gemm_out(
    const unsigned short* __restrict__ ctx,  // [M][E]
    const unsigned short* __restrict__ Wob,  // [E][E]
    float* __restrict__ out)                 // [M][E] fp32
{
    __shared__ unsigned short As[128*64];
    __shared__ unsigned short Bs[128*64];
    const int tid = threadIdx.x;
    const int w = tid >> 6, lane = tid & 63, quad = lane >> 4, col = lane & 15;
    const int wm = (w & 1) * 64, wn = (w >> 1) * 64;
    const int m0 = blockIdx.x * 128, n0 = blockIdx.y * 128;
    const int srow = lane >> 3, schunk = (lane & 7) * 8;

    f32x4 acc[4][4] = {};
    for (int k0 = 0; k0 < E_; k0 += 64) {
        #pragma unroll
        for (int c = 0; c < 4; c++) {
            int row = w*32 + c*8 + srow;
            gload_lds16(&ctx[(size_t)(m0+row)*E_ + k0 + schunk], &As[(w*32 + c*8)*64]);
            gload_lds16(&Wob[(size_t)(n0+row)*E_ + k0 + schunk], &Bs[(w*32 + c*8)*64]);
        }
        __syncthreads();
        #pragma unroll
        for (int kk = 0; kk < 64; kk += 32) {
            short8 a[4], b[4];
            #pragma unroll
            for (int i = 0; i < 4; i++)
                a[i] = *(const short8*)&As[(wm + i*16 + col)*64 + kk + quad*8];
            #pragma unroll
            for (int j = 0; j < 4; j++)
                b[j] = *(const short8*)&Bs[(wn + j*16 + col)*64 + kk + quad*8];
            #pragma unroll
            for (int i = 0; i < 4; i++)
                #pragma unroll
                for (int j = 0; j < 4; j++)
                    acc[i][j] = __builtin_amdgcn_mfma_f32_16x16x32_bf16(a[i], b[j], acc[i][j], 0, 0, 0);
        }
        __syncthreads();
    }
    #pragma unroll
    for (int j = 0; j < 4; j++) {
        int n = n0 + wn + j*16 + col;
        #pragma unroll
        for (int i = 0; i < 4; i++)
            #pragma unroll
            for (int r = 0; r < 4; r++) {
                int m = m0 + wm + i*16 + quad*4 + r;
                out[(size_t)m*E_ + n] = acc[i][j][r];
            }
    }
}

// ---------------------------------------------------------------------------
// Flash attention: 64 queries per wave (2 q-groups of 32), 256 q per block.
// kf/vf LDS fragments read once per key-tile, reused by both q-groups.
// l by VALU rsum + end shuffle; P C->A transform with 1 shfl_xor per pair-slot.
// ---------------------------------------------------------------------------
#define LPK 72   // padded LDS row stride (elements)

__global__ __launch_bounds__(256, 2) void flash_attn(
    const unsigned short* __restrict__ qb,   // pre-scaled by QSCALE
    const unsigned short* __restrict__ kb,
    const unsigned short* __restrict__ vtb,
    unsigned short* __restrict__ ctx)        // [M][E] bf16
{
    __shared__ unsigned short Kt[64*LPK];    // [key][d]
    __shared__ unsigned short Vt[64*LPK];    // [d][key]
    const int tid = threadIdx.x;
    const int w = tid >> 6, lane = tid & 63, col = lane & 31, half = lane >> 5;
    const int q0 = blockIdx.x * 256;
    const int bh = blockIdx.y;

    union U8 { unsigned u[4]; short8 s8; };

    // Q B-frags for both q-groups
    short8 qf[2][4];
    #pragma unroll
    for (int qg = 0; qg < 2; qg++) {
        const unsigned short* qrow = qb + ((size_t)bh*S_ + q0 + w*64 + qg*32 + col)*DK_;
        #pragma unroll
        for (int c = 0; c < 4; c++)
            qf[qg][c] = *(const short8*)&qrow[c*16 + half*8];
    }

    float rsum[2] = {0.f, 0.f};
    f32x16 oacc[2][2] = {};

    for (int kt = 0; kt < S_; kt += 64) {
        __syncthreads();
        for (int i = tid; i < 512; i += 256) {
            int row = i >> 3, c8 = (i & 7) * 8;
            *(int4*)&Kt[row*LPK + c8] = *(const int4*)&kb [((size_t)bh*S_  + kt + row)*DK_ + c8];
            *(int4*)&Vt[row*LPK + c8] = *(const int4*)&vtb[((size_t)bh*DK_ + row)*S_ + kt + c8];
        }
        __syncthreads();

        #pragma unroll
        for (int t = 0; t < 2; t++) {
            // K fragments for this 32-key tile (q-independent)
            short8 kf[4];
            #pragma unroll
            for (int c = 0; c < 4; c++)
                kf[c] = *(const short8*)&Kt[(t*32 + col)*LPK + c*16 + half*8];
            // V fragments for this tile (q-independent)
            short8 vf[2][2];
            #pragma unroll
            for (int kc = 0; kc < 2; kc++)
                #pragma unroll
                for (int dt = 0; dt < 2; dt++)
                    vf[kc][dt] = *(const short8*)&Vt[(dt*32 + col)*LPK + t*32 + kc*16 + half*8];

            #pragma unroll
            for (int qg = 0; qg < 2; qg++) {
                // S^T = K.Q^T
                f32x16 sacc = {};
                #pragma unroll
                for (int c = 0; c < 4; c++)
                    sacc = __builtin_amdgcn_mfma_f32_32x32x16_bf16(kf[c], qf[qg][c], sacc, 0, 0, 0);
                // p = exp2(score); pack pairs via v_perm (hi-16 truncation)
                unsigned pk[4][2];
                #pragma unroll
                for (int rg = 0; rg < 4; rg++) {
                    float p0 = __builtin_amdgcn_exp2f(sacc[rg*4+0]);
                    float p1 = __builtin_amdgcn_exp2f(sacc[rg*4+1]);
                    float p2 = __builtin_amdgcn_exp2f(sacc[rg*4+2]);
                    float p3 = __builtin_amdgcn_exp2f(sacc[rg*4+3]);
                    rsum[qg] += (p0 + p1) + (p2 + p3);
                    pk[rg][0] = __builtin_amdgcn_perm(__float_as_uint(p1), __float_as_uint(p0), 0x07060302u);
                    pk[rg][1] = __builtin_amdgcn_perm(__float_as_uint(p3), __float_as_uint(p2), 0x07060302u);
                }
                // PV over the two 16-key chunks
                #pragma unroll
                for (int kc = 0; kc < 2; kc++) {
                    const int lo = 2*kc, hi = 2*kc + 1;
                    // one shuffle transports both directions (pre-select by half)
                    unsigned t0 = half ? pk[lo][0] : pk[hi][0];
                    unsigned t1 = half ? pk[lo][1] : pk[hi][1];
                    unsigned r0 = __shfl_xor((int)t0, 32);
                    unsigned r1 = __shfl_xor((int)t1, 32);
                    U8 pa;
                    pa.u[0] = half ? r0 : pk[lo][0];
                    pa.u[1] = half ? r1 : pk[lo][1];
                    pa.u[2] = half ? pk[hi][0] : r0;
                    pa.u[3] = half ? pk[hi][1] : r1;
                    #pragma unroll
                    for (int dt = 0; dt < 2; dt++)
                        oacc[qg][dt] = __builtin_amdgcn_mfma_f32_32x32x16_bf16(pa.s8, vf[kc][dt], oacc[qg][dt], 0, 0, 0);
                }
            }
        }
    }

    // epilogue: l(q=col) = rsum(half0)+rsum(half1); redistribute inv(l) to C rows
    const int b = bh >> 4, h = bh & 15;
    #pragma unroll
    for (int qg = 0; qg < 2; qg++) {
        float l = rsum[qg] + __shfl_xor(rsum[qg], 32);
        float inv = 1.0f / l;                // lane holds inv for q = col (this qg)
        #pragma unroll
        for (int rg = 0; rg < 4; rg++)
            #pragma unroll
            for (int rr = 0; rr < 4; rr++) {
                int row = rr + rg*8 + half*4;
                float invr = __shfl(inv, row);   // from lane col=row (half0 segment)
                int s = q0 + w*64 + qg*32 + row;
                size_t rowoff = ((size_t)(b*S_ + s))*E_ + h*64;
                #pragma unroll
                for (int dt = 0; dt < 2; dt++)
                    ctx[rowoff + dt*32 + col] = f2b(oacc[qg][dt][rg*4 + rr] * invr);
            }
    }
}

extern "C" void kernel_launch(void* const* d_in, const int* in_sizes, int n_in,
                              void* d_out, int out_size, void* d_ws, size_t ws_size,
                              hipStream_t stream) {
    (void)in_sizes; (void)n_in; (void)out_size; (void)ws_size;
    const float* x     = (const float*)d_in[0];
    const float* Wq    = (const float*)d_in[1];
    const float* Wk    = (const float*)d_in[2];
    const float* Wv    = (const float*)d_in[3];
    const float* Wo    = (const float*)d_in[4];
    const float* theta = (const float*)d_in[5];
    float* out = (float*)d_out;

    unsigned short* ws  = (unsigned short*)d_ws;
    unsigned short* xb  = ws;                                    // M*E
    unsigned short* Wb  = xb  + (size_t)M_*E_;                   // 3*E*E
    unsigned short* Wob = Wb  + (size_t)3*E_*E_;                 // E*E
    unsigned short* qb  = Wob + (size_t)E_*E_;
    unsigned short* kb  = qb  + (size_t)B_*H_*S_*DK_;
    unsigned short* vtb = kb  + (size_t)B_*H_*S_*DK_;
    unsigned short* ctx = xb;                                    // alias (xb dead after gemm_qkv)

    cvt_all<<<(XN4 + 4*WN4)/256, 256, 0, stream>>>(x, Wq, Wk, Wv, Wo, xb, Wb, Wob);

    gemm_qkv<<<dim3(M_/128, E_/128, 3), 256, 0, stream>>>(xb, Wb, theta, qb, kb, vtb);
    flash_attn<<<dim3(S_/256, B_*H_), 256, 0, stream>>>(qb, kb, vtb, ctx);
    gemm_out<<<dim3(M_/128, E_/128), 256, 0, stream>>>(ctx, Wob, out);
}